// Round 19
// baseline (299.278 us; speedup 1.0000x reference)
//
#include <hip/hip_runtime.h>
#include <stdint.h>

#define BN 8
#define TN 4096
#define CN 512
#define TA 2048
#define RR 1024
#define BASEB 1024
#define MROWS 3072
#define KC 64
#define NCHUNK (CN / KC)
#define CAP 96
#define DCAP 32

typedef _Float16 f16x8 __attribute__((ext_vector_type(8)));
typedef float f32x4 __attribute__((ext_vector_type(4)));
typedef __attribute__((address_space(3))) uint32_t lds_u32_t;
typedef __attribute__((address_space(1))) const uint32_t g_u32_t;

__device__ __forceinline__ unsigned ofloat(float f) {
    unsigned u = __float_as_uint(f);
    return (u & 0x80000000u) ? ~u : (u | 0x80000000u);
}
__device__ __forceinline__ float unofloat(unsigned u) {
    unsigned v = (u & 0x80000000u) ? (u ^ 0x80000000u) : ~u;
    return __uint_as_float(v);
}

// ---------- kernel 1: normalize k rows -> H plane in K-CHUNKED layout ------
// plane[b][kc][node][KC=64]; folds nodekey/cnt/maxHH/dcnt init.
__global__ __launch_bounds__(256) void split_kernel(const float* __restrict__ k,
        _Float16* __restrict__ Ahi, _Float16* __restrict__ Bhi,
        float* __restrict__ invA, float* __restrict__ invB,
        float* __restrict__ nHa, float* __restrict__ nLa,
        float* __restrict__ Pq, float* __restrict__ Qq,
        unsigned long long* __restrict__ nodekey,
        int* __restrict__ cnt, unsigned* __restrict__ maxHH,
        int* __restrict__ dcnt) {
    int row = blockIdx.x * 4 + (threadIdx.x >> 6);
    int lane = threadIdx.x & 63;
    const float* p = k + (size_t)row * CN;
    float4 v1 = *(const float4*)(p + lane * 8);
    float4 v2 = *(const float4*)(p + lane * 8 + 4);
    float s = v1.x*v1.x + v1.y*v1.y + v1.z*v1.z + v1.w*v1.w
            + v2.x*v2.x + v2.y*v2.y + v2.z*v2.z + v2.w*v2.w;
    #pragma unroll
    for (int off = 32; off > 0; off >>= 1) s += __shfl_xor(s, off);
    float inv = 1.0f / (sqrtf(s) + 1e-12f);
    float sc = 1024.0f * inv;                 // exact (power of 2 scale)
    float m[8] = {v1.x*sc, v1.y*sc, v1.z*sc, v1.w*sc,
                  v2.x*sc, v2.y*sc, v2.z*sc, v2.w*sc};
    f16x8 H;
    float h2 = 0.f, l2 = 0.f;
    #pragma unroll
    for (int jj = 0; jj < 8; ++jj) {
        _Float16 h = (_Float16)m[jj];
        H[jj] = h;
        float hf = (float)h;
        float lf = m[jj] - hf;
        h2 += hf * hf;
        l2 += lf * lf;
    }
    #pragma unroll
    for (int off = 32; off > 0; off >>= 1) {
        h2 += __shfl_xor(h2, off);
        l2 += __shfl_xor(l2, off);
    }
    float nh = sqrtf(h2), nl = sqrtf(l2);
    int b = row >> 12;
    int tt = row & 4095;
    int node = tt >> 1;
    size_t dst = (((size_t)(b * NCHUNK + (lane >> 3)) * TA + node)) * KC
               + (lane & 7) * 8;
    if (tt & 1) {
        *(f16x8*)(Bhi + dst) = H;
        if (lane == 0) {
            invB[b * TA + node] = inv;
            Pq[b * TA + node] = nl + 1.2f + 4e-5f * nh;
            Qq[b * TA + node] = nh + nl + 1050.0f;
            nodekey[b * TA + node] =
                (((unsigned long long)0x007FFFFFu) << 32) | 0xFFFFFFFFull;
            cnt[b * TA + node] = 0;
            maxHH[b * TA + node] = 0u;
            dcnt[b * TA + node] = 0;
        }
    } else {
        *(f16x8*)(Ahi + dst) = H;
        if (lane == 0) {
            invA[b * TA + node] = inv;
            nHa[b * TA + node] = nh;
            nLa[b * TA + node] = nl;
        }
    }
}

// ---------- kernel 2: B-stationary HH MFMA + certified candidate emission --
// 1D grid 4096 (XCD-batch affinity), 256 thr = 4 waves, tile 128i x 64j.
// B panel (64 rows x full K=512) staged ONCE in 64KB LDS -> ONE barrier in
// the whole kernel; A fragments stream global->reg (L2-resident), so the
// K-loop is barrier-free and the compiler pipelines loads under MFMA.
// Wave owns 32 i-rows x all 64 j -> per-row max is wave-local.
__global__ __launch_bounds__(256, 2) void score_bstat_kernel(
        const _Float16* __restrict__ Ahi, const _Float16* __restrict__ Bhi,
        const float* __restrict__ nHa, const float* __restrict__ nLa,
        const float* __restrict__ Pq, const float* __restrict__ Qq,
        int* __restrict__ cnt, unsigned* __restrict__ maxHH,
        int* __restrict__ candJ, float* __restrict__ candS) {
    __shared__ _Float16 ldsB[64 * CN];       // 64 KB: B rows j0..j0+63, all K
    const int lid = blockIdx.x;
    const int b  = lid & 7;                  // XCD-batch affinity (4096%8==0)
    const int t  = lid >> 3;                 // 0..511 tiles/batch
    const int i0 = (t & 15) << 7;            // 16 i-tiles of 128
    const int j0 = (t >> 4) << 6;            // 32 j-tiles of 64
    const int tid = threadIdx.x;
    const int lane = tid & 63;
    const int w = tid >> 6;                  // wave w: i-rows [i0+w*32, +32)

    const size_t chunkstride = (size_t)TA * KC;
    const size_t batchbase = (size_t)b * NCHUNK * chunkstride;

    // ---- stage B panel once: 4096 x 16B slots, swizzled source seg
    // (same sg^(node&7) involution as the r14-proven kernel, 0 conflicts) ----
    #pragma unroll
    for (int it = 0; it < 16; ++it) {
        int s = it * 256 + tid;              // 16B-slot index 0..4095
        int node = s >> 6;                   // 0..63
        int w6 = s & 63;
        int kc = w6 >> 3, sl = w6 & 7;
        const _Float16* gp = Bhi + batchbase + (size_t)kc * chunkstride
            + (size_t)(j0 + node) * KC + ((sl ^ (node & 7)) * 8);
        __builtin_amdgcn_global_load_lds((g_u32_t*)gp,
            (lds_u32_t*)(ldsB + s * 8), 16, 0, 0);
    }
    __syncthreads();                         // the ONLY barrier

    const int fr = lane & 15, ks = lane >> 4;
    f32x4 acc[2][4];
    #pragma unroll
    for (int m = 0; m < 2; ++m)
        #pragma unroll
        for (int n = 0; n < 4; ++n) acc[m][n] = (f32x4){0.f, 0.f, 0.f, 0.f};

    // per-lane A base (global, K-chunked layout; no swizzle needed)
    const _Float16* aBase = Ahi + batchbase
        + (size_t)(i0 + w * 32 + fr) * KC + ks * 8;
    // kc-invariant B LDS offsets (f16 units), swizzle undone on read
    int bq[4][2];
    #pragma unroll
    for (int n = 0; n < 4; ++n) {
        int nb = n * 16 + fr;
        #pragma unroll
        for (int kk = 0; kk < 2; ++kk)
            bq[n][kk] = nb * CN + ((((kk << 2) + ks) ^ (nb & 7)) * 8);
    }

    #pragma unroll 2
    for (int kc = 0; kc < NCHUNK; ++kc) {
        f16x8 a[2][2];
        #pragma unroll
        for (int m = 0; m < 2; ++m)
            #pragma unroll
            for (int kk = 0; kk < 2; ++kk)
                a[m][kk] = *(const f16x8*)(aBase + (size_t)kc * chunkstride
                                           + m * (16 * KC) + kk * 32);
        #pragma unroll
        for (int kk = 0; kk < 2; ++kk)
            #pragma unroll
            for (int n = 0; n < 4; ++n) {
                f16x8 bh = *(const f16x8*)(&ldsB[bq[n][kk] + kc * KC]);
                #pragma unroll
                for (int m = 0; m < 2; ++m)
                    acc[m][n] = __builtin_amdgcn_mfma_f32_16x16x32_f16(
                        a[m][kk], bh, acc[m][n], 0, 0, 0);
            }
    }

    // ---- epilogue: wave-local row max over this block's 64 j ----
    float Pj[4], Qj[4];
    #pragma unroll
    for (int n = 0; n < 4; ++n) {
        int j = j0 + n * 16 + fr;
        Pj[n] = Pq[b * TA + j];
        Qj[n] = Qq[b * TA + j];
    }
    #pragma unroll
    for (int m = 0; m < 2; ++m)
        #pragma unroll
        for (int reg = 0; reg < 4; ++reg) {
            float M = acc[m][0][reg];
            #pragma unroll
            for (int n = 1; n < 4; ++n) M = fmaxf(M, acc[m][n][reg]);
            #pragma unroll
            for (int mm2 = 8; mm2 > 0; mm2 >>= 1)
                M = fmaxf(M, __shfl_xor(M, mm2, 16));
            int i = i0 + w * 32 + m * 16 + ks * 4 + reg;
            if (fr == 0)
                atomicMax(&maxHH[b * TA + i], ofloat(M));
            float ha = nHa[b * TA + i], la = nLa[b * TA + i];
            #pragma unroll
            for (int n = 0; n < 4; ++n) {
                float s = acc[m][n][reg];
                if (s >= M - (ha * Pj[n] + la * Qj[n])) {
                    int j = j0 + n * 16 + fr;
                    int idx = atomicAdd(&cnt[b * TA + i], 1);
                    if (idx < CAP) {
                        candJ[(size_t)(b * TA + i) * CAP + idx] = j;
                        candS[(size_t)(b * TA + i) * CAP + idx] = s;
                    }
                }
            }
        }
}

// ---------- kernel 3: exact fp32 rescore of candidates -> nodekey ----------
__global__ __launch_bounds__(256) void rescore_kernel(const float* __restrict__ k,
        const float* __restrict__ invA, const float* __restrict__ invB,
        const float* __restrict__ nHa, const float* __restrict__ nLa,
        const float* __restrict__ Pq, const float* __restrict__ Qq,
        const int* __restrict__ cnt, const unsigned* __restrict__ maxHH,
        const int* __restrict__ candJ, const float* __restrict__ candS,
        unsigned long long* __restrict__ nodekey) {
    const int b = blockIdx.y;
    const int wv = threadIdx.x >> 6;
    const int lane = threadIdx.x & 63;
    const int i = blockIdx.x * 4 + wv;
    if (i == 0) return;                      // PROTECT_CLS: keep -inf init
    const size_t base = (size_t)b * TA;
    float inva = invA[base + i];
    const float* ka = k + ((size_t)b * TN + 2 * i) * CN + lane * 8;
    float a[8];
    #pragma unroll
    for (int e = 0; e < 8; ++e) a[e] = ka[e] * inva;
    int c_n = cnt[base + i];
    float gmax = unofloat(maxHH[base + i]);
    float ha = nHa[base + i], la = nLa[base + i];
    unsigned bhi = 0u, blo = 0u;

    if (c_n <= CAP) {
        for (int c = 0; c < c_n; ++c) {
            int j = candJ[(base + i) * CAP + c];
            float s = candS[(base + i) * CAP + c];
            if (s < gmax - (ha * Pq[base + j] + la * Qq[base + j])) continue;
            float invb = invB[base + j];
            const float* kb = k + ((size_t)b * TN + 2 * j + 1) * CN + lane * 8;
            float d = 0.f;
            #pragma unroll
            for (int e = 0; e < 8; ++e) d += a[e] * (kb[e] * invb);
            #pragma unroll
            for (int off = 32; off > 0; off >>= 1) d += __shfl_xor(d, off);
            unsigned khi = ofloat(d), klo = 0xFFFFFFFFu - (unsigned)j;
            if (khi > bhi || (khi == bhi && klo > blo)) { bhi = khi; blo = klo; }
        }
    } else {
        for (int j = 0; j < TA; ++j) {       // never expected; correctness net
            float invb = invB[base + j];
            const float* kb = k + ((size_t)b * TN + 2 * j + 1) * CN + lane * 8;
            float d = 0.f;
            #pragma unroll
            for (int e = 0; e < 8; ++e) d += a[e] * (kb[e] * invb);
            #pragma unroll
            for (int off = 32; off > 0; off >>= 1) d += __shfl_xor(d, off);
            unsigned khi = ofloat(d), klo = 0xFFFFFFFFu - (unsigned)j;
            if (khi > bhi || (khi == bhi && klo > blo)) { bhi = khi; blo = klo; }
        }
    }
    if (lane == 0)
        nodekey[base + i] = (((unsigned long long)bhi) << 32) | blo;
}

// ---------- kernel 4a: parallel counting rank -> membership flag -----------
__global__ __launch_bounds__(256) void rank_flag_kernel(
        const unsigned long long* __restrict__ nodekey,
        int* __restrict__ is_src) {
    __shared__ unsigned long long K[2048];
    const int b = blockIdx.y;
    const int t = threadIdx.x;
    for (int i = t; i < 2048; i += 256) {
        unsigned hi = (unsigned)(nodekey[b * TA + i] >> 32);
        K[i] = (((unsigned long long)hi) << 32) | (unsigned)(2047 - i);
    }
    __syncthreads();
    const int i = blockIdx.x * 256 + t;
    const unsigned long long ki = K[i];
    int rank = 0;
    #pragma unroll 8
    for (int j = 0; j < 2048; ++j) rank += (K[j] > ki) ? 1 : 0;
    is_src[b * TA + i] = (rank < RR) ? 1 : 0;
}

// ---------- kernel 4b: per-batch scan + source_index + gather structures ---
__global__ __launch_bounds__(1024) void scan_si_kernel(const int* __restrict__ is_src,
        const unsigned long long* __restrict__ nodekey,
        float* __restrict__ out_si, int* __restrict__ rank2node,
        int* __restrict__ dcnt, int* __restrict__ dlist,
        int* __restrict__ aidx) {
    __shared__ int ps[2048];
    __shared__ unsigned char fl[2048];
    const int b = blockIdx.x;
    const int t = threadIdx.x;
    int s0 = is_src[b * TA + t];
    int s1 = is_src[b * TA + 1024 + t];
    int f0 = 1 - s0, f1 = 1 - s1;
    fl[t] = (unsigned char)s0;
    fl[t + 1024] = (unsigned char)s1;
    ps[t] = f0;
    ps[t + 1024] = f1;
    __syncthreads();
    for (int off = 1; off < 2048; off <<= 1) {
        int v0 = (t >= off) ? ps[t - off] : 0;
        int v1 = ((t + 1024) >= off) ? ps[t + 1024 - off] : 0;
        __syncthreads();
        ps[t] += v0;
        ps[t + 1024] += v1;
        __syncthreads();
    }
    int u0 = ps[t] - f0, u1 = ps[t + 1024] - f1;
    #pragma unroll
    for (int h = 0; h < 2; ++h) {
        int i = t + h * 1024;
        int u = h ? u1 : u0;
        int val;
        if (fl[i]) {
            unsigned j = 0xFFFFFFFFu - (unsigned)(nodekey[b * TA + i] & 0xFFFFFFFFull);
            val = BASEB + (int)j;
            int idx = atomicAdd(&dcnt[b * TA + (int)j], 1);
            aidx[b * TA + i] = idx;
            if (idx < DCAP)
                dlist[((size_t)b * TA + (int)j) * DCAP + idx] = i;
        } else {
            val = u;
            rank2node[b * BASEB + u] = i;
        }
        out_si[(size_t)b * TN + 2 * i]     = (float)val;
        out_si[(size_t)b * TN + 2 * i + 1] = (float)(BASEB + i);
    }
}

// ---------- kernel 5: build all output rows (one write per row, no atomics)
__global__ __launch_bounds__(128) void move_kernel(const float* __restrict__ x,
        const int* __restrict__ rank2node, const int* __restrict__ dcnt,
        const int* __restrict__ dlist, float* __restrict__ out) {
    const int b = blockIdx.y;
    const int r = blockIdx.x;
    float4* dst = (float4*)(out + ((size_t)b * MROWS + r) * CN);
    if (r < BASEB) {
        int i = rank2node[b * BASEB + r];
        const float4* src = (const float4*)(x + ((size_t)b * TN + 2 * i) * CN);
        dst[threadIdx.x] = src[threadIdx.x];
    } else {
        int j = r - BASEB;
        const float4* sd = (const float4*)(x + ((size_t)b * TN + 2 * j + 1) * CN);
        float4 v = sd[threadIdx.x];
        int c = dcnt[b * TA + j];
        if (c > DCAP) c = DCAP;
        for (int s = 0; s < c; ++s) {
            int i = dlist[((size_t)b * TA + j) * DCAP + s];
            const float4* ss = (const float4*)(x + ((size_t)b * TN + 2 * i) * CN);
            float4 w = ss[threadIdx.x];
            v.x += w.x; v.y += w.y; v.z += w.z; v.w += w.w;
        }
        dst[threadIdx.x] = v;
    }
}

// ---------- kernel 6: overflow fallback (srcs beyond DCAP; normally none) --
__global__ __launch_bounds__(256) void overflow_kernel(const float* __restrict__ x,
        const int* __restrict__ is_src, const int* __restrict__ aidx,
        const unsigned long long* __restrict__ nodekey,
        float* __restrict__ out) {
    const int b = blockIdx.y;
    const int i = blockIdx.x * 256 + threadIdx.x;
    if (!is_src[b * TA + i] || aidx[b * TA + i] < DCAP) return;
    unsigned j = 0xFFFFFFFFu - (unsigned)(nodekey[b * TA + i] & 0xFFFFFFFFull);
    const float* src = x + ((size_t)b * TN + 2 * i) * CN;
    float* dst = out + ((size_t)b * MROWS + BASEB + j) * CN;
    for (int c = 0; c < CN; ++c) atomicAdd(&dst[c], src[c]);
}

extern "C" void kernel_launch(void* const* d_in, const int* in_sizes, int n_in,
                              void* d_out, int out_size, void* d_ws, size_t ws_size,
                              hipStream_t stream) {
    const float* x = (const float*)d_in[0];
    const float* k = (const float*)d_in[1];
    float* out = (float*)d_out;
    float* out_si = out + (size_t)BN * MROWS * CN;

    char* ws = (char*)d_ws;
    const size_t PLANE = (size_t)BN * TA * CN;          // 8,388,608 elements
    _Float16* Ahi = (_Float16*)ws;
    _Float16* Bhi = Ahi + PLANE;
    char* tail = ws + 2 * PLANE * sizeof(_Float16);     // 32 MB
    const size_t NN = (size_t)BN * TA;                  // 16384 nodes
    float* invA = (float*)(tail);
    float* invB = invA + NN;
    float* nHa  = invB + NN;
    float* nLa  = nHa + NN;
    float* Pq   = nLa + NN;
    float* Qq   = Pq + NN;
    unsigned long long* nodekey = (unsigned long long*)(Qq + NN);
    int* cnt        = (int*)(nodekey + NN);
    unsigned* maxHH = (unsigned*)(cnt + NN);
    int* is_src     = (int*)(maxHH + NN);
    int* dcnt       = is_src + NN;
    int* aidx       = dcnt + NN;
    int* rank2node  = aidx + NN;                        // BN*BASEB
    int* candJ      = rank2node + (size_t)BN * BASEB;
    float* candS    = (float*)(candJ + NN * CAP);
    int* dlist      = (int*)(candS + NN * CAP);         // NN*DCAP ints (2MB)

    split_kernel<<<dim3(BN * TN / 4), dim3(256), 0, stream>>>(
        k, Ahi, Bhi, invA, invB, nHa, nLa, Pq, Qq, nodekey, cnt, maxHH, dcnt);
    score_bstat_kernel<<<dim3(4096), dim3(256), 0, stream>>>(
        Ahi, Bhi, nHa, nLa, Pq, Qq, cnt, maxHH, candJ, candS);
    rescore_kernel<<<dim3(512, BN), dim3(256), 0, stream>>>(
        k, invA, invB, nHa, nLa, Pq, Qq, cnt, maxHH, candJ, candS, nodekey);
    rank_flag_kernel<<<dim3(8, BN), dim3(256), 0, stream>>>(nodekey, is_src);
    scan_si_kernel<<<dim3(BN), dim3(1024), 0, stream>>>(
        is_src, nodekey, out_si, rank2node, dcnt, dlist, aidx);
    move_kernel<<<dim3(MROWS, BN), dim3(128), 0, stream>>>(
        x, rank2node, dcnt, dlist, out);
    overflow_kernel<<<dim3(TA / 256, BN), dim3(256), 0, stream>>>(
        x, is_src, aidx, nodekey, out);
}

// Round 20
// 182.132 us; speedup vs baseline: 1.6432x; 1.6432x over previous
//
#include <hip/hip_runtime.h>
#include <stdint.h>

#define BN 8
#define TN 4096
#define CN 512
#define TA 2048
#define RR 1024
#define BASEB 1024
#define MROWS 3072
#define KC 64
#define NCHUNK (CN / KC)
#define CAP 64
#define DCAP 32

typedef _Float16 f16x8 __attribute__((ext_vector_type(8)));
typedef float f32x4 __attribute__((ext_vector_type(4)));
typedef __attribute__((address_space(3))) uint32_t lds_u32_t;
typedef __attribute__((address_space(1))) const uint32_t g_u32_t;

__device__ __forceinline__ unsigned ofloat(float f) {
    unsigned u = __float_as_uint(f);
    return (u & 0x80000000u) ? ~u : (u | 0x80000000u);
}
__device__ __forceinline__ float unofloat(unsigned u) {
    unsigned v = (u & 0x80000000u) ? (u ^ 0x80000000u) : ~u;
    return __uint_as_float(v);
}

// ---------- kernel 1: normalize k rows -> H plane in K-CHUNKED layout ------
// plane[b][kc][node][KC=64]; folds nodekey/cnt/maxHH/dcnt init.
__global__ __launch_bounds__(256) void split_kernel(const float* __restrict__ k,
        _Float16* __restrict__ Ahi, _Float16* __restrict__ Bhi,
        float* __restrict__ invA, float* __restrict__ invB,
        float* __restrict__ nHa, float* __restrict__ nLa,
        float* __restrict__ Pq, float* __restrict__ Qq,
        unsigned long long* __restrict__ nodekey,
        int* __restrict__ cnt, unsigned* __restrict__ maxHH,
        int* __restrict__ dcnt) {
    int row = blockIdx.x * 4 + (threadIdx.x >> 6);
    int lane = threadIdx.x & 63;
    const float* p = k + (size_t)row * CN;
    float4 v1 = *(const float4*)(p + lane * 8);
    float4 v2 = *(const float4*)(p + lane * 8 + 4);
    float s = v1.x*v1.x + v1.y*v1.y + v1.z*v1.z + v1.w*v1.w
            + v2.x*v2.x + v2.y*v2.y + v2.z*v2.z + v2.w*v2.w;
    #pragma unroll
    for (int off = 32; off > 0; off >>= 1) s += __shfl_xor(s, off);
    float inv = 1.0f / (sqrtf(s) + 1e-12f);
    float sc = 1024.0f * inv;                 // exact (power of 2 scale)
    float m[8] = {v1.x*sc, v1.y*sc, v1.z*sc, v1.w*sc,
                  v2.x*sc, v2.y*sc, v2.z*sc, v2.w*sc};
    f16x8 H;
    float h2 = 0.f, l2 = 0.f;
    #pragma unroll
    for (int jj = 0; jj < 8; ++jj) {
        _Float16 h = (_Float16)m[jj];
        H[jj] = h;
        float hf = (float)h;
        float lf = m[jj] - hf;
        h2 += hf * hf;
        l2 += lf * lf;
    }
    #pragma unroll
    for (int off = 32; off > 0; off >>= 1) {
        h2 += __shfl_xor(h2, off);
        l2 += __shfl_xor(l2, off);
    }
    float nh = sqrtf(h2), nl = sqrtf(l2);
    int b = row >> 12;
    int tt = row & 4095;
    int node = tt >> 1;
    size_t dst = (((size_t)(b * NCHUNK + (lane >> 3)) * TA + node)) * KC
               + (lane & 7) * 8;
    if (tt & 1) {
        *(f16x8*)(Bhi + dst) = H;
        if (lane == 0) {
            invB[b * TA + node] = inv;
            Pq[b * TA + node] = nl + 1.2f + 4e-5f * nh;
            Qq[b * TA + node] = nh + nl + 1050.0f;
            nodekey[b * TA + node] =
                (((unsigned long long)0x007FFFFFu) << 32) | 0xFFFFFFFFull;
            cnt[b * TA + node] = 0;
            maxHH[b * TA + node] = 0u;
            dcnt[b * TA + node] = 0;
        }
    } else {
        *(f16x8*)(Ahi + dst) = H;
        if (lane == 0) {
            invA[b * TA + node] = inv;
            nHa[b * TA + node] = nh;
            nLa[b * TA + node] = nl;
        }
    }
}

// ---------- kernel 2: HH-only MFMA GEMM + certified candidate emission -----
// 1D grid 2048, 256 thr = 4 waves, 128x128 tile, KC=64, XCD-batch affinity
// (proven r17/r18: 85us, FETCH 25MB, 0 conflicts).
__global__ __launch_bounds__(256, 4) void score_hh_kernel(
        const _Float16* __restrict__ Ahi, const _Float16* __restrict__ Bhi,
        const float* __restrict__ nHa, const float* __restrict__ nLa,
        const float* __restrict__ Pq, const float* __restrict__ Qq,
        int* __restrict__ cnt, unsigned* __restrict__ maxHH,
        int* __restrict__ candJ, float* __restrict__ candS) {
    __shared__ _Float16 lds[2 * 128 * KC];   // A: [0,8192), B: [8192,16384)
    __shared__ float rowmax2[128][2];
    const int lid = blockIdx.x;
    const int b  = lid & 7;                  // XCD-batch affinity
    const int t  = lid >> 3;                 // 0..255 tile index
    const int i0 = (t & 15) << 7;
    const int j0 = (t >> 4) << 7;
    const int tid = threadIdx.x;
    const int lane = tid & 63;
    const int w = tid >> 6;
    const int wr = (w >> 1) * 64;
    const int wc = (w & 1) * 64;

    const size_t chunkstride = (size_t)TA * KC;
    const size_t batchbase = (size_t)b * NCHUNK * chunkstride;
    const _Float16* pbase[2] = { Ahi + batchbase + (size_t)i0 * KC,
                                 Bhi + batchbase + (size_t)j0 * KC };
    int srcoff[8];
    #pragma unroll
    for (int i = 0; i < 8; ++i) {
        int s = (i & 3) * 256 + tid;
        int n = s >> 3, sg = s & 7;
        srcoff[i] = n * KC + ((sg ^ (n & 7)) * 8);
    }

    f32x4 acc[4][4];
    #pragma unroll
    for (int m = 0; m < 4; ++m)
        #pragma unroll
        for (int n = 0; n < 4; ++n) acc[m][n] = (f32x4){0.f, 0.f, 0.f, 0.f};

    const int fr = lane & 15, ks = lane >> 4;
    int rowbaseA[4], rowbaseB[4];
    #pragma unroll
    for (int m = 0; m < 4; ++m) rowbaseA[m] = (wr + m * 16 + fr) * KC;
    #pragma unroll
    for (int n = 0; n < 4; ++n) rowbaseB[n] = (wc + n * 16 + fr) * KC;

    for (int kt = 0; kt < NCHUNK; ++kt) {
        const size_t cb = (size_t)kt * chunkstride;
        #pragma unroll
        for (int i = 0; i < 8; ++i) {
            _Float16* lp = lds + (i >> 2) * 8192 + ((i & 3) * 256 + tid) * 8;
            __builtin_amdgcn_global_load_lds(
                (g_u32_t*)(pbase[i >> 2] + cb + srcoff[i]),
                (lds_u32_t*)lp, 16, 0, 0);
        }
        __syncthreads();
        #pragma unroll
        for (int kk = 0; kk < 2; ++kk) {
            const int slo = (((kk << 2) + ks) ^ (fr & 7)) * 8;
            f16x8 bh[4];
            #pragma unroll
            for (int n = 0; n < 4; ++n)
                bh[n] = *(const f16x8*)(&lds[8192 + rowbaseB[n] + slo]);
            #pragma unroll
            for (int m = 0; m < 4; ++m) {
                f16x8 ah = *(const f16x8*)(&lds[rowbaseA[m] + slo]);
                #pragma unroll
                for (int n = 0; n < 4; ++n)
                    acc[m][n] = __builtin_amdgcn_mfma_f32_16x16x32_f16(ah, bh[n], acc[m][n], 0, 0, 0);
            }
        }
        __syncthreads();
    }

    // ---- epilogue: wave row-max -> block row-max -> certified emission ----
    float wmax[4][4];
    #pragma unroll
    for (int m = 0; m < 4; ++m)
        #pragma unroll
        for (int reg = 0; reg < 4; ++reg) {
            float mx = acc[m][0][reg];
            #pragma unroll
            for (int n = 1; n < 4; ++n) mx = fmaxf(mx, acc[m][n][reg]);
            #pragma unroll
            for (int mm2 = 8; mm2 > 0; mm2 >>= 1)
                mx = fmaxf(mx, __shfl_xor(mx, mm2, 16));
            wmax[m][reg] = mx;
        }
    if (fr == 0) {
        #pragma unroll
        for (int m = 0; m < 4; ++m)
            #pragma unroll
            for (int reg = 0; reg < 4; ++reg) {
                int r = wr + m * 16 + ks * 4 + reg;
                rowmax2[r][w & 1] = wmax[m][reg];
            }
    }
    __syncthreads();
    if (fr == 0) {
        #pragma unroll
        for (int m = 0; m < 4; ++m)
            #pragma unroll
            for (int reg = 0; reg < 4; ++reg) {
                int r = wr + m * 16 + ks * 4 + reg;
                atomicMax(&maxHH[b * TA + i0 + r], ofloat(wmax[m][reg]));
            }
    }
    float Pj[4], Qj[4];
    #pragma unroll
    for (int n = 0; n < 4; ++n) {
        int j = j0 + wc + n * 16 + fr;
        Pj[n] = Pq[b * TA + j];
        Qj[n] = Qq[b * TA + j];
    }
    #pragma unroll
    for (int m = 0; m < 4; ++m)
        #pragma unroll
        for (int reg = 0; reg < 4; ++reg) {
            int r = wr + m * 16 + ks * 4 + reg;
            int i = i0 + r;
            float M = fmaxf(rowmax2[r][0], rowmax2[r][1]);
            float ha = nHa[b * TA + i], la = nLa[b * TA + i];
            #pragma unroll
            for (int n = 0; n < 4; ++n) {
                float s = acc[m][n][reg];
                if (s >= M - (ha * Pj[n] + la * Qj[n])) {
                    int j = j0 + wc + n * 16 + fr;
                    int idx = atomicAdd(&cnt[b * TA + i], 1);
                    if (idx < CAP) {
                        candJ[(size_t)(b * TA + i) * CAP + idx] = j;
                        candS[(size_t)(b * TA + i) * CAP + idx] = s;
                    }
                }
            }
        }
}

// ---------- kernel 3: exact fp32 rescore of candidates -> nodekey ----------
__global__ __launch_bounds__(256) void rescore_kernel(const float* __restrict__ k,
        const float* __restrict__ invA, const float* __restrict__ invB,
        const float* __restrict__ nHa, const float* __restrict__ nLa,
        const float* __restrict__ Pq, const float* __restrict__ Qq,
        const int* __restrict__ cnt, const unsigned* __restrict__ maxHH,
        const int* __restrict__ candJ, const float* __restrict__ candS,
        unsigned long long* __restrict__ nodekey) {
    const int b = blockIdx.y;
    const int wv = threadIdx.x >> 6;
    const int lane = threadIdx.x & 63;
    const int i = blockIdx.x * 4 + wv;
    if (i == 0) return;                      // PROTECT_CLS: keep -inf init
    const size_t base = (size_t)b * TA;
    float inva = invA[base + i];
    const float* ka = k + ((size_t)b * TN + 2 * i) * CN + lane * 8;
    float a[8];
    #pragma unroll
    for (int e = 0; e < 8; ++e) a[e] = ka[e] * inva;
    int c_n = cnt[base + i];
    float gmax = unofloat(maxHH[base + i]);
    float ha = nHa[base + i], la = nLa[base + i];
    unsigned bhi = 0u, blo = 0u;

    if (c_n <= CAP) {
        for (int c = 0; c < c_n; ++c) {
            int j = candJ[(base + i) * CAP + c];
            float s = candS[(base + i) * CAP + c];
            if (s < gmax - (ha * Pq[base + j] + la * Qq[base + j])) continue;
            float invb = invB[base + j];
            const float* kb = k + ((size_t)b * TN + 2 * j + 1) * CN + lane * 8;
            float d = 0.f;
            #pragma unroll
            for (int e = 0; e < 8; ++e) d += a[e] * (kb[e] * invb);
            #pragma unroll
            for (int off = 32; off > 0; off >>= 1) d += __shfl_xor(d, off);
            unsigned khi = ofloat(d), klo = 0xFFFFFFFFu - (unsigned)j;
            if (khi > bhi || (khi == bhi && klo > blo)) { bhi = khi; blo = klo; }
        }
    } else {
        for (int j = 0; j < TA; ++j) {       // never expected; correctness net
            float invb = invB[base + j];
            const float* kb = k + ((size_t)b * TN + 2 * j + 1) * CN + lane * 8;
            float d = 0.f;
            #pragma unroll
            for (int e = 0; e < 8; ++e) d += a[e] * (kb[e] * invb);
            #pragma unroll
            for (int off = 32; off > 0; off >>= 1) d += __shfl_xor(d, off);
            unsigned khi = ofloat(d), klo = 0xFFFFFFFFu - (unsigned)j;
            if (khi > bhi || (khi == bhi && klo > blo)) { bhi = khi; blo = klo; }
        }
    }
    if (lane == 0)
        nodekey[base + i] = (((unsigned long long)bhi) << 32) | blo;
}

// ---------- kernel 4a: parallel counting rank -> membership flag -----------
__global__ __launch_bounds__(256) void rank_flag_kernel(
        const unsigned long long* __restrict__ nodekey,
        int* __restrict__ is_src) {
    __shared__ unsigned long long K[2048];
    const int b = blockIdx.y;
    const int t = threadIdx.x;
    for (int i = t; i < 2048; i += 256) {
        unsigned hi = (unsigned)(nodekey[b * TA + i] >> 32);
        K[i] = (((unsigned long long)hi) << 32) | (unsigned)(2047 - i);
    }
    __syncthreads();
    const int i = blockIdx.x * 256 + t;
    const unsigned long long ki = K[i];
    int rank = 0;
    #pragma unroll 8
    for (int j = 0; j < 2048; ++j) rank += (K[j] > ki) ? 1 : 0;
    is_src[b * TA + i] = (rank < RR) ? 1 : 0;
}

// ---------- kernel 4b: per-batch scan + source_index + gather structures ---
__global__ __launch_bounds__(1024) void scan_si_kernel(const int* __restrict__ is_src,
        const unsigned long long* __restrict__ nodekey,
        float* __restrict__ out_si, int* __restrict__ rank2node,
        int* __restrict__ dcnt, int* __restrict__ dlist,
        int* __restrict__ aidx) {
    __shared__ int ps[2048];
    __shared__ unsigned char fl[2048];
    const int b = blockIdx.x;
    const int t = threadIdx.x;
    int s0 = is_src[b * TA + t];
    int s1 = is_src[b * TA + 1024 + t];
    int f0 = 1 - s0, f1 = 1 - s1;
    fl[t] = (unsigned char)s0;
    fl[t + 1024] = (unsigned char)s1;
    ps[t] = f0;
    ps[t + 1024] = f1;
    __syncthreads();
    for (int off = 1; off < 2048; off <<= 1) {
        int v0 = (t >= off) ? ps[t - off] : 0;
        int v1 = ((t + 1024) >= off) ? ps[t + 1024 - off] : 0;
        __syncthreads();
        ps[t] += v0;
        ps[t + 1024] += v1;
        __syncthreads();
    }
    int u0 = ps[t] - f0, u1 = ps[t + 1024] - f1;
    #pragma unroll
    for (int h = 0; h < 2; ++h) {
        int i = t + h * 1024;
        int u = h ? u1 : u0;
        int val;
        if (fl[i]) {
            unsigned j = 0xFFFFFFFFu - (unsigned)(nodekey[b * TA + i] & 0xFFFFFFFFull);
            val = BASEB + (int)j;
            int idx = atomicAdd(&dcnt[b * TA + (int)j], 1);
            aidx[b * TA + i] = idx;
            if (idx < DCAP)
                dlist[((size_t)b * TA + (int)j) * DCAP + idx] = i;
        } else {
            val = u;
            rank2node[b * BASEB + u] = i;
        }
        out_si[(size_t)b * TN + 2 * i]     = (float)val;
        out_si[(size_t)b * TN + 2 * i + 1] = (float)(BASEB + i);
    }
}

// ---------- kernel 5: build all output rows (one write per row, no atomics)
// grid (3072, 8) x 128 thr (float4/thread covers 512 floats).
__global__ __launch_bounds__(128) void move_kernel(const float* __restrict__ x,
        const int* __restrict__ rank2node, const int* __restrict__ dcnt,
        const int* __restrict__ dlist, float* __restrict__ out) {
    const int b = blockIdx.y;
    const int r = blockIdx.x;
    float4* dst = (float4*)(out + ((size_t)b * MROWS + r) * CN);
    if (r < BASEB) {
        int i = rank2node[b * BASEB + r];
        const float4* src = (const float4*)(x + ((size_t)b * TN + 2 * i) * CN);
        dst[threadIdx.x] = src[threadIdx.x];
    } else {
        int j = r - BASEB;
        const float4* sd = (const float4*)(x + ((size_t)b * TN + 2 * j + 1) * CN);
        float4 v = sd[threadIdx.x];
        int c = dcnt[b * TA + j];
        if (c > DCAP) c = DCAP;
        for (int s = 0; s < c; ++s) {
            int i = dlist[((size_t)b * TA + j) * DCAP + s];
            const float4* ss = (const float4*)(x + ((size_t)b * TN + 2 * i) * CN);
            float4 w = ss[threadIdx.x];
            v.x += w.x; v.y += w.y; v.z += w.z; v.w += w.w;
        }
        dst[threadIdx.x] = v;
    }
}

// ---------- kernel 6: overflow fallback (srcs beyond DCAP; normally none) --
__global__ __launch_bounds__(256) void overflow_kernel(const float* __restrict__ x,
        const int* __restrict__ is_src, const int* __restrict__ aidx,
        const unsigned long long* __restrict__ nodekey,
        float* __restrict__ out) {
    const int b = blockIdx.y;
    const int i = blockIdx.x * 256 + threadIdx.x;
    if (!is_src[b * TA + i] || aidx[b * TA + i] < DCAP) return;
    unsigned j = 0xFFFFFFFFu - (unsigned)(nodekey[b * TA + i] & 0xFFFFFFFFull);
    const float* src = x + ((size_t)b * TN + 2 * i) * CN;
    float* dst = out + ((size_t)b * MROWS + BASEB + j) * CN;
    for (int c = 0; c < CN; ++c) atomicAdd(&dst[c], src[c]);
}

extern "C" void kernel_launch(void* const* d_in, const int* in_sizes, int n_in,
                              void* d_out, int out_size, void* d_ws, size_t ws_size,
                              hipStream_t stream) {
    const float* x = (const float*)d_in[0];
    const float* k = (const float*)d_in[1];
    float* out = (float*)d_out;
    float* out_si = out + (size_t)BN * MROWS * CN;

    char* ws = (char*)d_ws;
    const size_t PLANE = (size_t)BN * TA * CN;          // 8,388,608 elements
    _Float16* Ahi = (_Float16*)ws;
    _Float16* Bhi = Ahi + PLANE;
    char* tail = ws + 2 * PLANE * sizeof(_Float16);     // 32 MB
    const size_t NN = (size_t)BN * TA;                  // 16384 nodes
    float* invA = (float*)(tail);
    float* invB = invA + NN;
    float* nHa  = invB + NN;
    float* nLa  = nHa + NN;
    float* Pq   = nLa + NN;
    float* Qq   = Pq + NN;
    unsigned long long* nodekey = (unsigned long long*)(Qq + NN);
    int* cnt        = (int*)(nodekey + NN);
    unsigned* maxHH = (unsigned*)(cnt + NN);
    int* is_src     = (int*)(maxHH + NN);
    int* dcnt       = is_src + NN;
    int* aidx       = dcnt + NN;
    int* rank2node  = aidx + NN;                        // BN*BASEB
    int* candJ      = rank2node + (size_t)BN * BASEB;
    float* candS    = (float*)(candJ + NN * CAP);
    int* dlist      = (int*)(candS + NN * CAP);         // NN*DCAP ints (2MB)

    split_kernel<<<dim3(BN * TN / 4), dim3(256), 0, stream>>>(
        k, Ahi, Bhi, invA, invB, nHa, nLa, Pq, Qq, nodekey, cnt, maxHH, dcnt);
    score_hh_kernel<<<dim3(2048), dim3(256), 0, stream>>>(
        Ahi, Bhi, nHa, nLa, Pq, Qq, cnt, maxHH, candJ, candS);
    rescore_kernel<<<dim3(512, BN), dim3(256), 0, stream>>>(
        k, invA, invB, nHa, nLa, Pq, Qq, cnt, maxHH, candJ, candS, nodekey);
    rank_flag_kernel<<<dim3(8, BN), dim3(256), 0, stream>>>(nodekey, is_src);
    scan_si_kernel<<<dim3(BN), dim3(1024), 0, stream>>>(
        is_src, nodekey, out_si, rank2node, dcnt, dlist, aidx);
    move_kernel<<<dim3(MROWS, BN), dim3(128), 0, stream>>>(
        x, rank2node, dcnt, dlist, out);
    overflow_kernel<<<dim3(TA / 256, BN), dim3(256), 0, stream>>>(
        x, is_src, aidx, nodekey, out);
}